// Round 1
// baseline (16.098 us; speedup 1.0000x reference)
//
#include <hip/hip_runtime.h>
#include <hip/hip_bf16.h>

// Problem constants (from reference setup_inputs)
#define BB 64
#define SS 2048
#define HH 768
// marker ids
#define ENT1_START 1
#define ENT1_END   2
#define ENT2_START 3
#define ENT2_END   4

// One block per batch row.
//  Phase 1: scan ids[b, :] for first occurrence of marker ids 1..4 (LDS atomicMin,
//           matches jnp.argmax-on-bool first-occurrence semantics).
//  Phase 2: dot the span rows of sequence_output with the matching half of W,
//           divide by span count, add bias. Terms are zeroed unless both markers
//           found AND count > 0 (matches `ok = valid & (cnt > 0)`).
__global__ __launch_bounds__(256)
void relcls_fused_kernel(const int* __restrict__ ids,
                         const float* __restrict__ seq,
                         const float* __restrict__ W,
                         const float* __restrict__ bias,
                         float* __restrict__ out) {
    const int b   = blockIdx.x;
    const int tid = threadIdx.x;

    __shared__ int first[4];          // first index of marker id (1..4), SS if absent
    if (tid < 4) first[tid] = SS;
    __syncthreads();

    // ---- Phase 1: find markers ----
    const int* row = ids + (long)b * SS;
    for (int s = tid; s < SS; s += 256) {
        int t = row[s];
        unsigned m = (unsigned)(t - 1);
        if (m < 4u) atomicMin(&first[m], s);
    }
    __syncthreads();

    const int s1 = first[0], e1 = first[1];
    const int s2 = first[2], e2 = first[3];
    const bool found1 = (s1 < SS) && (e1 < SS);
    const bool found2 = (s2 < SS) && (e2 < SS);
    const int cnt1 = e1 - s1 - 1;     // # of positions with s1 < p < e1
    const int cnt2 = e2 - s2 - 1;
    const bool ok1 = found1 && (cnt1 > 0);
    const bool ok2 = found2 && (cnt2 > 0);

    // ---- Phase 2: span dot products ----
    float acc1 = 0.0f;
    float acc2 = 0.0f;

    if (ok1) {
        for (int p = s1 + 1; p < e1; ++p) {
            const float* r = seq + ((long)b * SS + p) * HH;
            #pragma unroll
            for (int h = tid; h < HH; h += 256) {
                acc1 += r[h] * W[h];
            }
        }
    }
    if (ok2) {
        for (int p = s2 + 1; p < e2; ++p) {
            const float* r = seq + ((long)b * SS + p) * HH;
            #pragma unroll
            for (int h = tid; h < HH; h += 256) {
                acc2 += r[h] * W[HH + h];
            }
        }
    }

    // ---- Block reduction (wave64 shuffle, then cross-wave via LDS) ----
    #pragma unroll
    for (int off = 32; off > 0; off >>= 1) {
        acc1 += __shfl_down(acc1, off, 64);
        acc2 += __shfl_down(acc2, off, 64);
    }
    __shared__ float red1[4];
    __shared__ float red2[4];
    const int wave = tid >> 6;
    if ((tid & 63) == 0) { red1[wave] = acc1; red2[wave] = acc2; }
    __syncthreads();

    if (tid == 0) {
        float t1 = red1[0] + red1[1] + red1[2] + red1[3];
        float t2 = red2[0] + red2[1] + red2[2] + red2[3];
        float r = bias[0];
        if (ok1) r += t1 / (float)cnt1;
        if (ok2) r += t2 / (float)cnt2;
        out[b] = r;
    }
}

extern "C" void kernel_launch(void* const* d_in, const int* in_sizes, int n_in,
                              void* d_out, int out_size, void* d_ws, size_t ws_size,
                              hipStream_t stream) {
    const int*   ids  = (const int*)d_in[0];     // input_ids [B,S]
    // d_in[1] = attention_mask (unused by the reference computation)
    const float* seq  = (const float*)d_in[2];   // sequence_output [B,S,H]
    const float* W    = (const float*)d_in[3];   // [1, 2H]
    const float* bias = (const float*)d_in[4];   // [1]
    float*       out  = (float*)d_out;           // [B]

    relcls_fused_kernel<<<BB, 256, 0, stream>>>(ids, seq, W, bias, out);
}

// Round 2
// 9.316 us; speedup vs baseline: 1.7279x; 1.7279x over previous
//
#include <hip/hip_runtime.h>
#include <hip/hip_bf16.h>

// Problem constants (from reference setup_inputs)
#define BB 64
#define SS 2048
#define HH 768
#define NT 768          // block size: h == tid, 12 waves
#define MAXC 16         // compile-time span-length cap for the fast path

// One block per batch row.
//  Phase 1: scan ids[b,:] for first occurrence of marker ids 1..4 (LDS atomicMin).
//  Phase 2: fast path — load MAXC rows per span unconditionally (all loads in
//           flight, one HBM latency), mask accumulation by c < cnt.
//           Fallback serial loop for out-of-cap spans (correctness for any input).
__global__ __launch_bounds__(NT)
void relcls_fused_kernel(const int* __restrict__ ids,
                         const float* __restrict__ seq,
                         const float* __restrict__ W,
                         const float* __restrict__ bias,
                         float* __restrict__ out) {
    const int b   = blockIdx.x;
    const int tid = threadIdx.x;

    __shared__ int first[4];          // first index of marker id (1..4), SS if absent
    if (tid < 4) first[tid] = SS;

    // Prefetch the weight column for this h (independent of the scan).
    const float w1 = W[tid];
    const float w2 = W[HH + tid];

    __syncthreads();                  // first[] initialized

    // ---- Phase 1: find markers ----
    const int* row = ids + (long)b * SS;
    #pragma unroll
    for (int s = tid; s < SS; s += NT) {   // <= 3 iterations, compile-time bounds
        int t = row[s];
        unsigned m = (unsigned)(t - 1);
        if (m < 4u) atomicMin(&first[m], s);
    }
    __syncthreads();

    const int s1 = first[0], e1 = first[1];
    const int s2 = first[2], e2 = first[3];
    const bool found1 = (s1 < SS) && (e1 < SS);
    const bool found2 = (s2 < SS) && (e2 < SS);
    const int cnt1 = e1 - s1 - 1;     // # of positions with s1 < p < e1
    const int cnt2 = e2 - s2 - 1;
    const bool ok1 = found1 && (cnt1 > 0);
    const bool ok2 = found2 && (cnt2 > 0);
    const int n1 = ok1 ? cnt1 : 0;    // rows to accumulate
    const int n2 = ok2 ? cnt2 : 0;

    const float* base = seq + (long)b * SS * HH;
    float sum1 = 0.0f, sum2 = 0.0f;

    const bool fast1 = (n1 == 0) || (n1 <= MAXC && s1 + MAXC < SS);
    const bool fast2 = (n2 == 0) || (n2 <= MAXC && s2 + MAXC < SS);

    if (fast1 && fast2) {
        // Dummy-safe row bases: if a span is inactive point at row 0 (still in-bounds).
        const float* r1 = base + (long)(n1 ? (s1 + 1) : 0) * HH + tid;
        const float* r2 = base + (long)(n2 ? (s2 + 1) : 0) * HH + tid;
        float v1[MAXC], v2[MAXC];
        #pragma unroll
        for (int c = 0; c < MAXC; ++c) v1[c] = r1[(long)c * HH];   // all loads issued,
        #pragma unroll
        for (int c = 0; c < MAXC; ++c) v2[c] = r2[(long)c * HH];   // one latency wait
        #pragma unroll
        for (int c = 0; c < MAXC; ++c) {
            sum1 += (c < n1) ? v1[c] : 0.0f;
            sum2 += (c < n2) ? v2[c] : 0.0f;
        }
    } else {
        // General path (arbitrary span lengths) — serial but correct.
        for (int c = 0; c < n1; ++c) sum1 += base[(long)(s1 + 1 + c) * HH + tid];
        for (int c = 0; c < n2; ++c) sum2 += base[(long)(s2 + 1 + c) * HH + tid];
    }

    const float inv1 = ok1 ? 1.0f / (float)cnt1 : 0.0f;
    const float inv2 = ok2 ? 1.0f / (float)cnt2 : 0.0f;
    float val = sum1 * w1 * inv1 + sum2 * w2 * inv2;

    // ---- Block reduction: wave64 shuffle, then cross-wave via LDS ----
    #pragma unroll
    for (int off = 32; off > 0; off >>= 1) val += __shfl_down(val, off, 64);

    __shared__ float red[NT / 64];
    if ((tid & 63) == 0) red[tid >> 6] = val;
    __syncthreads();

    if (tid == 0) {
        float t = bias[0];
        #pragma unroll
        for (int i = 0; i < NT / 64; ++i) t += red[i];
        out[b] = t;
    }
}

extern "C" void kernel_launch(void* const* d_in, const int* in_sizes, int n_in,
                              void* d_out, int out_size, void* d_ws, size_t ws_size,
                              hipStream_t stream) {
    const int*   ids  = (const int*)d_in[0];     // input_ids [B,S]
    // d_in[1] = attention_mask (unused by the reference computation)
    const float* seq  = (const float*)d_in[2];   // sequence_output [B,S,H]
    const float* W    = (const float*)d_in[3];   // [1, 2H]
    const float* bias = (const float*)d_in[4];   // [1]
    float*       out  = (float*)d_out;           // [B]

    relcls_fused_kernel<<<BB, NT, 0, stream>>>(ids, seq, W, bias, out);
}